// Round 12
// baseline (261.046 us; speedup 1.0000x reference)
//
#include <hip/hip_runtime.h>
#include <hip/hip_cooperative_groups.h>
#include <math.h>

namespace cg = cooperative_groups;

#define NN 50000
#define NE 800000
#define DD 128
#define DOUT 40
#define BN_EPS_F 1e-5f
#define BSTRIDE 64           // bucket slots per node (max deg ~45; P(>64) ~ 1e-14)
#define NPX (NN / 8)         // 6250 nodes per XCD partition
#define EPB 1024             // edges per chunk: 4 edges/thread via int4
#define BUCKET_BLOCKS (((NE + EPB - 1) / EPB) * 8)   // 6256
#define X2BF_BLOCKS 6250
#define WPREP_BLOCKS ((5 * 16384 + 255) / 256)       // 320
#define HSTRIDE 136          // h-tile pad: 272B row stride -> 16B-aligned b128 reads

typedef __attribute__((ext_vector_type(8))) short bf16x8;
typedef __attribute__((ext_vector_type(4))) float f32x4;

static __device__ __forceinline__ unsigned short f2bf(float f) {
  unsigned u = __float_as_uint(f);
  unsigned r = (u + 0x7FFFu + ((u >> 16) & 1u)) >> 16;
  return (unsigned short)r;
}
static __device__ __forceinline__ float bf2f(unsigned short u) {
  return __uint_as_float((unsigned)u << 16);
}

// ---------------- zero cnt + stats ----------------
__global__ void k_zero(int* __restrict__ cnt, float* __restrict__ stats) {
  int i = blockIdx.x * 256 + threadIdx.x;
  if (i < NN) cnt[i] = 0;
  if (i < 4 * DD) stats[i] = 0.f;
}

// ---- fused: XCD-partitioned bucket build | x->bf16 | weight frag shuffle ----
__global__ void k_bucketprep(const int* __restrict__ srcI, const int* __restrict__ dstI,
                             int* __restrict__ cnt, unsigned short* __restrict__ bkt,
                             const float4* __restrict__ x, ushort4* __restrict__ xb,
                             const float* __restrict__ W0, const float* __restrict__ W1,
                             const float* __restrict__ W2, const float* __restrict__ W3,
                             const float* __restrict__ W4, unsigned short* __restrict__ wf) {
  int b = blockIdx.x;
  if (b < BUCKET_BLOCKS) {
    int xcd = b & 7;
    int chunk = b >> 3;
    int lo = xcd * NPX, hi = lo + NPX;
    int e0 = chunk * EPB + threadIdx.x * 4;
    if (e0 < NE) {
      int4 d4 = *(const int4*)(dstI + e0);
      int4 s4 = *(const int4*)(srcI + e0);
      int dd[4] = {d4.x, d4.y, d4.z, d4.w};
      int ss[4] = {s4.x, s4.y, s4.z, s4.w};
#pragma unroll
      for (int i = 0; i < 4; i++) {
        int d = dd[i];
        if (d >= lo && d < hi) {
          int r = atomicAdd(&cnt[d], 1);
          if (r < BSTRIDE) bkt[(size_t)d * BSTRIDE + r] = (unsigned short)ss[i];
        }
      }
    }
  } else if (b < BUCKET_BLOCKS + X2BF_BLOCKS) {
    int i = (b - BUCKET_BLOCKS) * 256 + threadIdx.x;
    if (i < NN * 32) {
      float4 v = x[i];
      ushort4 r;
      r.x = f2bf(v.x); r.y = f2bf(v.y); r.z = f2bf(v.z); r.w = f2bf(v.w);
      xb[i] = r;
    }
  } else {
    int fid = (b - BUCKET_BLOCKS - X2BF_BLOCKS) * 256 + threadIdx.x;
    if (fid >= 5 * 16384) return;
    int g = fid >> 14;
    int r = fid & 16383;
    int i = r & 7;
    int lane = (r >> 3) & 63;
    int ks = (r >> 9) & 3;
    int ct = r >> 11;
    int k = ks * 32 + (lane >> 4) * 8 + i;
    int col = ct * 16 + (lane & 15);
    const float* Wp = (g == 0) ? W0 : (g == 1) ? W1 : (g == 2) ? W2 : (g == 3) ? W3 : W4;
    float w = Wp[k * DD + col];
    unsigned short hi = f2bf(w);
    unsigned short lo = f2bf(w - bf2f(hi));
    wf[g * 32768 + r] = hi;
    wf[g * 32768 + 16384 + r] = lo;
  }
}

// ---------------- bf16 gather aggregation over buckets (32 lanes/row) ----------------
__global__ void k_aggr_bf(const ushort4* __restrict__ x, const int* __restrict__ cnt,
                          const unsigned short* __restrict__ bkt,
                          ushort4* __restrict__ out) {
  int tid = blockIdx.x * 256 + threadIdx.x;
  int node = tid >> 5;
  if (node >= NN) return;
  int c = tid & 31;
  int cn = cnt[node];
  cn = (cn < BSTRIDE) ? cn : BSTRIDE;
  const unsigned short* bp = bkt + (size_t)node * BSTRIDE;
  ushort4 sv = x[node * 32 + c];
  float ax = bf2f(sv.x), ay = bf2f(sv.y), az = bf2f(sv.z), aw = bf2f(sv.w);
  int j = 0;
  for (; j + 3 < cn; j += 4) {
    int s0 = bp[j], s1 = bp[j + 1], s2 = bp[j + 2], s3 = bp[j + 3];
    ushort4 v0 = x[s0 * 32 + c];
    ushort4 v1 = x[s1 * 32 + c];
    ushort4 v2 = x[s2 * 32 + c];
    ushort4 v3 = x[s3 * 32 + c];
    ax += bf2f(v0.x) + bf2f(v1.x) + bf2f(v2.x) + bf2f(v3.x);
    ay += bf2f(v0.y) + bf2f(v1.y) + bf2f(v2.y) + bf2f(v3.y);
    az += bf2f(v0.z) + bf2f(v1.z) + bf2f(v2.z) + bf2f(v3.z);
    aw += bf2f(v0.w) + bf2f(v1.w) + bf2f(v2.w) + bf2f(v3.w);
  }
  for (; j < cn; j++) {
    int s0 = bp[j];
    ushort4 v0 = x[s0 * 32 + c];
    ax += bf2f(v0.x); ay += bf2f(v0.y); az += bf2f(v0.z); aw += bf2f(v0.w);
  }
  ushort4 r;
  r.x = f2bf(ax); r.y = f2bf(ay); r.z = f2bf(az); r.w = f2bf(aw);
  out[node * 32 + c] = r;
}

// ------- cooperative fused conv: GEMM1 -> stats -> grid.sync -> BN -> GEMM2 -------
// grid 256 x 512 (1 block/CU, 134 KB LDS), 2 row-passes of 128 rows/block.
// acc held in registers across grid.sync; h1 never touches global memory.
__global__ __launch_bounds__(512) void k_conv(
    const unsigned short* __restrict__ in,
    const unsigned short* __restrict__ wf1, const float* __restrict__ b1v,
    const unsigned short* __restrict__ wf2, const float* __restrict__ b2v,
    const float* __restrict__ gamma, const float* __restrict__ beta,
    float* __restrict__ stats, unsigned short* __restrict__ outB) {
  __shared__ __align__(16) char R1[65536];   // W1 frags; then h-tile (transpose)
  __shared__ __align__(16) char R2[65536];   // W2 frags
  __shared__ float scs[DD], shs[DD], lb1[DD], lb2[DD], ls[DD], lq[DD];
  int tid = threadIdx.x;
  int lane = tid & 63, wv = tid >> 6;
  int kq = (lane >> 4) * 8;
  int rb0 = blockIdx.x * 128 + wv * 16;
  int rb[2] = {rb0, rb0 + 32768};

  // ---- A prefetch (both passes, before W staging) ----
  bf16x8 araw[2][4];
  bf16x8 zz = {0, 0, 0, 0, 0, 0, 0, 0};
#pragma unroll
  for (int p = 0; p < 2; p++) {
    int row = rb[p] + (lane & 15);
    bool v = row < NN;
    const unsigned short* ap = in + (size_t)row * DD + kq;
#pragma unroll
    for (int ks = 0; ks < 4; ks++)
      araw[p][ks] = v ? *(const bf16x8*)(ap + ks * 32) : zz;
  }

  // ---- stage W1 -> R1, W2 -> R2 (64 KB each) ----
  {
    const float4* s1 = (const float4*)wf1;
    const float4* s2 = (const float4*)wf2;
    float4* d1 = (float4*)R1;
    float4* d2 = (float4*)R2;
#pragma unroll
    for (int it = 0; it < 8; it++) {
      d1[it * 512 + tid] = s1[it * 512 + tid];
      d2[it * 512 + tid] = s2[it * 512 + tid];
    }
  }
  if (tid < DD) {
    lb1[tid] = b1v[tid];
    lb2[tid] = b2v[tid];
    ls[tid] = 0.f; lq[tid] = 0.f;
  }
  __syncthreads();

  // ---- GEMM1 (both passes) ----
  f32x4 acc[2][8];
#pragma unroll
  for (int p = 0; p < 2; p++)
#pragma unroll
    for (int ct = 0; ct < 8; ct++) acc[p][ct] = (f32x4){0.f, 0.f, 0.f, 0.f};
  {
    const bf16x8* l1 = (const bf16x8*)R1;
#pragma unroll
    for (int ks = 0; ks < 4; ks++) {
#pragma unroll
      for (int ct = 0; ct < 8; ct++) {
        bf16x8 bh = l1[(ct * 4 + ks) * 64 + lane];
        bf16x8 bl = l1[2048 + (ct * 4 + ks) * 64 + lane];
        acc[0][ct] = __builtin_amdgcn_mfma_f32_16x16x32_bf16(araw[0][ks], bh, acc[0][ct], 0, 0, 0);
        acc[0][ct] = __builtin_amdgcn_mfma_f32_16x16x32_bf16(araw[0][ks], bl, acc[0][ct], 0, 0, 0);
        acc[1][ct] = __builtin_amdgcn_mfma_f32_16x16x32_bf16(araw[1][ks], bh, acc[1][ct], 0, 0, 0);
        acc[1][ct] = __builtin_amdgcn_mfma_f32_16x16x32_bf16(araw[1][ks], bl, acc[1][ct], 0, 0, 0);
      }
    }
  }

  // ---- col stats of h1 = acc + b1 (pre-BN, fp32) ----
  {
    int fr0 = (lane >> 4) * 4;
#pragma unroll
    for (int ct = 0; ct < 8; ct++) {
      int col = ct * 16 + (lane & 15);
      float bb = lb1[col];
      float s = 0.f, q = 0.f;
#pragma unroll
      for (int p = 0; p < 2; p++) {
        int r0 = rb[p] + fr0;
#pragma unroll
        for (int j = 0; j < 4; j++) {
          if (r0 + j < NN) {
            float v = acc[p][ct][j] + bb;
            s += v; q += v * v;
          }
        }
      }
      s += __shfl_xor(s, 16); s += __shfl_xor(s, 32);
      q += __shfl_xor(q, 16); q += __shfl_xor(q, 32);
      if ((lane >> 4) == 0) {
        atomicAdd(&ls[col], s);
        atomicAdd(&lq[col], q);
      }
    }
  }
  __syncthreads();
  if (tid < DD) {
    atomicAdd(&stats[tid], ls[tid]);
    atomicAdd(&stats[DD + tid], lq[tid]);
  }

  cg::this_grid().sync();

  if (tid < DD) {
    float mu  = stats[tid] * (1.0f / NN);
    float var = stats[DD + tid] * (1.0f / NN) - mu * mu;
    float sc  = gamma[tid] * rsqrtf(var + BN_EPS_F);
    scs[tid] = sc;
    shs[tid] = beta[tid] - mu * sc;
  }
  __syncthreads();

  // ---- per pass: BN in-register -> h-tile (R1) -> A2 frags -> GEMM2 -> out ----
  unsigned short* hs = (unsigned short*)R1;        // [128][HSTRIDE] bf16
  const bf16x8* l2 = (const bf16x8*)R2;
#pragma unroll
  for (int p = 0; p < 2; p++) {
    {
      int fr0 = (lane >> 4) * 4;
      int lr0 = wv * 16 + fr0;
#pragma unroll
      for (int ct = 0; ct < 8; ct++) {
        int col = ct * 16 + (lane & 15);
        float sc = scs[col], sh = shs[col], bb = lb1[col];
#pragma unroll
        for (int j = 0; j < 4; j++) {
          float v = fmaxf((acc[p][ct][j] + bb) * sc + sh, 0.f);
          hs[(lr0 + j) * HSTRIDE + col] = f2bf(v);
        }
      }
    }
    __syncthreads();
    bf16x8 a2[4];
    {
      int lr = wv * 16 + (lane & 15);
#pragma unroll
      for (int ks = 0; ks < 4; ks++)
        a2[ks] = *(const bf16x8*)(hs + lr * HSTRIDE + ks * 32 + kq);
    }
    f32x4 o[8];
#pragma unroll
    for (int ct = 0; ct < 8; ct++) o[ct] = (f32x4){0.f, 0.f, 0.f, 0.f};
#pragma unroll
    for (int ks = 0; ks < 4; ks++) {
#pragma unroll
      for (int ct = 0; ct < 8; ct++) {
        bf16x8 bh = l2[(ct * 4 + ks) * 64 + lane];
        bf16x8 bl = l2[2048 + (ct * 4 + ks) * 64 + lane];
        o[ct] = __builtin_amdgcn_mfma_f32_16x16x32_bf16(a2[ks], bh, o[ct], 0, 0, 0);
        o[ct] = __builtin_amdgcn_mfma_f32_16x16x32_bf16(a2[ks], bl, o[ct], 0, 0, 0);
      }
    }
    {
      int fr0 = (lane >> 4) * 4;
      int r0 = rb[p] + fr0;
#pragma unroll
      for (int ct = 0; ct < 8; ct++) {
        int col = ct * 16 + (lane & 15);
        float bb = lb2[col];
#pragma unroll
        for (int j = 0; j < 4; j++) {
          int row = r0 + j;
          if (row < NN) {
            float v = fmaxf(o[ct][j] + bb, 0.f);
            outB[(size_t)row * DD + col] = f2bf(v);
          }
        }
      }
    }
    __syncthreads();
  }
}

// ---------------- head: log_softmax(relu(in@Wl1+bl1) @ Wl2 + bl2) ----------------
__global__ __launch_bounds__(512) void k_headm(
    const unsigned short* __restrict__ in, const unsigned short* __restrict__ wf,
    const float* __restrict__ bias, float* __restrict__ outF,
    const float* __restrict__ W2h, const float* __restrict__ b2h) {
  __shared__ __align__(16) char smem[65536];   // W frags; reused as h-tile + W2
  __shared__ float lbias[DD];
  short* lw = (short*)smem;
  int tid = threadIdx.x;
  int lane = tid & 63, wv = tid >> 6;
  int rbase = blockIdx.x * 128 + wv * 16;
  int kq = (lane >> 4) * 8;

  bf16x8 araw[4];
  {
    int row = rbase + (lane & 15);
    bool v = row < NN;
    const unsigned short* ap = in + (size_t)row * DD + kq;
    bf16x8 zz = {0, 0, 0, 0, 0, 0, 0, 0};
#pragma unroll
    for (int ks = 0; ks < 4; ks++)
      araw[ks] = v ? *(const bf16x8*)(ap + ks * 32) : zz;
  }
  {
    const float4* src = (const float4*)wf;
    float4* dst = (float4*)lw;
#pragma unroll
    for (int it = 0; it < 8; it++) dst[it * 512 + tid] = src[it * 512 + tid];
  }
  if (tid < DD) lbias[tid] = bias[tid];
  __syncthreads();

  f32x4 acc[8];
#pragma unroll
  for (int ct = 0; ct < 8; ct++) acc[ct] = (f32x4){0.f, 0.f, 0.f, 0.f};
  const bf16x8* lwv = (const bf16x8*)lw;
#pragma unroll
  for (int ks = 0; ks < 4; ks++) {
#pragma unroll
    for (int ct = 0; ct < 8; ct++) {
      bf16x8 bh = lwv[(ct * 4 + ks) * 64 + lane];
      bf16x8 bl = lwv[2048 + (ct * 4 + ks) * 64 + lane];
      acc[ct] = __builtin_amdgcn_mfma_f32_16x16x32_bf16(araw[ks], bh, acc[ct], 0, 0, 0);
      acc[ct] = __builtin_amdgcn_mfma_f32_16x16x32_bf16(araw[ks], bl, acc[ct], 0, 0, 0);
    }
  }

  unsigned short* hs = (unsigned short*)smem;        // [128][132] bf16
  float* W2s = (float*)(smem + 33792);               // [128][40] f32
  __syncthreads();
  {
    int lr0 = wv * 16 + (lane >> 4) * 4;
#pragma unroll
    for (int ct = 0; ct < 8; ct++) {
      int col = ct * 16 + (lane & 15);
      float bb = lbias[col];
#pragma unroll
      for (int j = 0; j < 4; j++) {
        float v = fmaxf(acc[ct][j] + bb, 0.f);
        hs[(lr0 + j) * 132 + col] = f2bf(v);
      }
    }
    const float4* W2g = (const float4*)W2h;
    float4* W2s4 = (float4*)W2s;
#pragma unroll
    for (int it = 0; it < 3; it++) {
      int idx = it * 512 + tid;
      if (idx < 1280) W2s4[idx] = W2g[idx];
    }
  }
  __syncthreads();
  int lrow = tid >> 2, q = tid & 3;
  int grow = blockIdx.x * 128 + lrow;
  float a2[40];
#pragma unroll
  for (int j = 0; j < 40; j++) a2[j] = 0.f;
  for (int kk = 0; kk < 32; kk++) {
    int k = kk * 4 + q;
    float hv = bf2f(hs[lrow * 132 + k]);
    const float4* wrow = (const float4*)(W2s + k * DOUT);
#pragma unroll
    for (int j4 = 0; j4 < 10; j4++) {
      float4 w = wrow[j4];
      a2[j4 * 4 + 0] += hv * w.x;
      a2[j4 * 4 + 1] += hv * w.y;
      a2[j4 * 4 + 2] += hv * w.z;
      a2[j4 * 4 + 3] += hv * w.w;
    }
  }
#pragma unroll
  for (int j = 0; j < 40; j++) {
    a2[j] += __shfl_xor(a2[j], 1);
    a2[j] += __shfl_xor(a2[j], 2);
  }
  if (q == 0 && grow < NN) {
    const float4* b24 = (const float4*)b2h;
    float m = -INFINITY;
#pragma unroll
    for (int j4 = 0; j4 < 10; j4++) {
      float4 bb = b24[j4];
      a2[j4 * 4 + 0] += bb.x; a2[j4 * 4 + 1] += bb.y;
      a2[j4 * 4 + 2] += bb.z; a2[j4 * 4 + 3] += bb.w;
    }
#pragma unroll
    for (int j = 0; j < 40; j++) m = fmaxf(m, a2[j]);
    float s = 0.f;
#pragma unroll
    for (int j = 0; j < 40; j++) s += expf(a2[j] - m);
    float d = m + logf(s);
    float4* out4 = (float4*)(outF + (size_t)grow * DOUT);
#pragma unroll
    for (int j4 = 0; j4 < 10; j4++) {
      float4 v = make_float4(a2[j4 * 4 + 0] - d, a2[j4 * 4 + 1] - d,
                             a2[j4 * 4 + 2] - d, a2[j4 * 4 + 3] - d);
      out4[j4] = v;
    }
  }
}

extern "C" void kernel_launch(void* const* d_in, const int* in_sizes, int n_in,
                              void* d_out, int out_size, void* d_ws, size_t ws_size,
                              hipStream_t stream) {
  const float* x   = (const float*)d_in[0];
  const int*   ei  = (const int*)d_in[1];
  const float* W1a = (const float*)d_in[2];
  const float* b1a = (const float*)d_in[3];
  const float* g1  = (const float*)d_in[4];
  const float* be1 = (const float*)d_in[5];
  const float* W2a = (const float*)d_in[6];
  const float* b2a = (const float*)d_in[7];
  const float* W1b = (const float*)d_in[8];
  const float* b1b = (const float*)d_in[9];
  const float* g2  = (const float*)d_in[10];
  const float* be2 = (const float*)d_in[11];
  const float* W2b = (const float*)d_in[12];
  const float* b2b = (const float*)d_in[13];
  const float* Wl1 = (const float*)d_in[14];
  const float* bl1 = (const float*)d_in[15];
  const float* Wl2 = (const float*)d_in[16];
  const float* bl2 = (const float*)d_in[17];
  float* out = (float*)d_out;

  unsigned short* bufX = (unsigned short*)d_ws;           // N x 128 bf16
  unsigned short* bufA = bufX + (size_t)NN * DD;          // N x 128 bf16
  unsigned short* bufB = bufA + (size_t)NN * DD;          // N x 128 bf16
  float* stats1 = (float*)(bufB + (size_t)NN * DD);       // 256
  float* stats2 = stats1 + 2 * DD;                        // 256
  int*   cnt    = (int*)(stats2 + 2 * DD);                // N
  unsigned short* bkt = (unsigned short*)(cnt + NN);      // N x BSTRIDE
  size_t wfOff = (((size_t)(bkt + (size_t)NN * BSTRIDE) - (size_t)d_ws) + 15) & ~(size_t)15;
  unsigned short* wfrag = (unsigned short*)((char*)d_ws + wfOff);

  const int* srcI = ei;
  const int* dstI = ei + NE;

  dim3 blk(256);
  int aggrGrid = (NN * 32 + 255) / 256;                  // 6250
  int headGrid = (NN + 127) / 128;                       // 391
  int bpGrid   = BUCKET_BLOCKS + X2BF_BLOCKS + WPREP_BLOCKS;
  int zeroGrid = (NN + 255) / 256;

  // ---- setup ----
  k_zero<<<zeroGrid, blk, 0, stream>>>(cnt, stats1);
  k_bucketprep<<<bpGrid, blk, 0, stream>>>(srcI, dstI, cnt, bkt, (const float4*)x,
                                           (ushort4*)bufX, W1a, W2a, W1b, W2b, Wl1, wfrag);

  // ---- conv1 ----
  k_aggr_bf<<<aggrGrid, blk, 0, stream>>>((const ushort4*)bufX, cnt, bkt, (ushort4*)bufA);
  {
    const unsigned short* cin = bufA;
    const unsigned short* cw1 = wfrag + 0 * 32768;
    const float* cb1 = b1a;
    const unsigned short* cw2 = wfrag + 1 * 32768;
    const float* cb2 = b2a;
    const float* cga = g1;
    const float* cbe = be1;
    float* cst = stats1;
    unsigned short* cout = bufB;
    void* cargs[] = {&cin, &cw1, &cb1, &cw2, &cb2, &cga, &cbe, &cst, &cout};
    hipLaunchCooperativeKernel((const void*)k_conv, dim3(256), dim3(512), cargs, 0, stream);
  }
  // ---- conv2 ----
  k_aggr_bf<<<aggrGrid, blk, 0, stream>>>((const ushort4*)bufB, cnt, bkt, (ushort4*)bufA);
  {
    const unsigned short* cin = bufA;
    const unsigned short* cw1 = wfrag + 2 * 32768;
    const float* cb1 = b1b;
    const unsigned short* cw2 = wfrag + 3 * 32768;
    const float* cb2 = b2b;
    const float* cga = g2;
    const float* cbe = be2;
    float* cst = stats2;
    unsigned short* cout = bufB;
    void* cargs[] = {&cin, &cw1, &cb1, &cw2, &cb2, &cga, &cbe, &cst, &cout};
    hipLaunchCooperativeKernel((const void*)k_conv, dim3(256), dim3(512), cargs, 0, stream);
  }
  // ---- head ----
  k_headm<<<headGrid, 512, 0, stream>>>(bufB, wfrag + 4 * 32768, bl1, out, Wl2, bl2);
}

// Round 13
// 203.005 us; speedup vs baseline: 1.2859x; 1.2859x over previous
//
#include <hip/hip_runtime.h>
#include <math.h>

#define NN 50000
#define NE 800000
#define DD 128
#define DOUT 40
#define BN_EPS_F 1e-5f
#define BSTRIDE 32           // bucket row = one 64B line (deg~Poisson(16); overflow list for >32)
#define OVF_MAX 8192
#define NPX (NN / 8)         // 6250 nodes per XCD partition
#define EPB 1024             // edges per chunk: 4 edges/thread via int4
#define BUCKET_BLOCKS (((NE + EPB - 1) / EPB) * 8)   // 6256
#define X2BF_BLOCKS 6250
#define WPREP_BLOCKS ((5 * 16384 + 255) / 256)       // 320

typedef __attribute__((ext_vector_type(8))) short bf16x8;
typedef __attribute__((ext_vector_type(4))) float f32x4;

static __device__ __forceinline__ unsigned short f2bf(float f) {
  unsigned u = __float_as_uint(f);
  unsigned r = (u + 0x7FFFu + ((u >> 16) & 1u)) >> 16;
  return (unsigned short)r;
}
static __device__ __forceinline__ float bf2f(unsigned short u) {
  return __uint_as_float((unsigned)u << 16);
}

// async global->LDS, 16B/lane; LDS dest = wave-uniform base + lane*16 (HW pattern)
static __device__ __forceinline__ void gload_lds16(const void* g, void* l) {
  __builtin_amdgcn_global_load_lds(
      (const __attribute__((address_space(1))) void*)g,
      (__attribute__((address_space(3))) void*)l, 16, 0, 0);
}

// ---------------- zero cnt + stats + overflow counter ----------------
__global__ void k_zero(int* __restrict__ cnt, float* __restrict__ stats,
                       int* __restrict__ ovfc) {
  int i = blockIdx.x * 256 + threadIdx.x;
  if (i < NN) cnt[i] = 0;
  if (i < 4 * DD) stats[i] = 0.f;
  if (i == 0) ovfc[0] = 0;
}

// ---- fused: XCD-partitioned bucket build | x->bf16 | weight frag shuffle ----
// bucket: blockIdx&7 = XCD-owned dst range (kills cross-XCD write bounce, r7);
// BSTRIDE=32 -> 64B/node row, per-XCD dirty set ~425 KB stays L2-resident (r13).
__global__ void k_bucketprep(const int* __restrict__ srcI, const int* __restrict__ dstI,
                             int* __restrict__ cnt, unsigned short* __restrict__ bkt,
                             int* __restrict__ ovfc, unsigned* __restrict__ ovf,
                             const float4* __restrict__ x, ushort4* __restrict__ xb,
                             const float* __restrict__ W0, const float* __restrict__ W1,
                             const float* __restrict__ W2, const float* __restrict__ W3,
                             const float* __restrict__ W4, unsigned short* __restrict__ wf) {
  int b = blockIdx.x;
  if (b < BUCKET_BLOCKS) {
    int xcd = b & 7;
    int chunk = b >> 3;
    int lo = xcd * NPX, hi = lo + NPX;
    int e0 = chunk * EPB + threadIdx.x * 4;
    if (e0 < NE) {
      int4 d4 = *(const int4*)(dstI + e0);
      int4 s4 = *(const int4*)(srcI + e0);
      int dd[4] = {d4.x, d4.y, d4.z, d4.w};
      int ss[4] = {s4.x, s4.y, s4.z, s4.w};
#pragma unroll
      for (int i = 0; i < 4; i++) {
        int d = dd[i];
        if (d >= lo && d < hi) {
          int r = atomicAdd(&cnt[d], 1);
          if (r < BSTRIDE) {
            bkt[(size_t)d * BSTRIDE + r] = (unsigned short)ss[i];
          } else {
            int o = atomicAdd(ovfc, 1);
            if (o < OVF_MAX) ovf[o] = ((unsigned)d << 16) | (unsigned)ss[i];
          }
        }
      }
    }
  } else if (b < BUCKET_BLOCKS + X2BF_BLOCKS) {
    int i = (b - BUCKET_BLOCKS) * 256 + threadIdx.x;
    if (i < NN * 32) {
      float4 v = x[i];
      ushort4 r;
      r.x = f2bf(v.x); r.y = f2bf(v.y); r.z = f2bf(v.z); r.w = f2bf(v.w);
      xb[i] = r;
    }
  } else {
    int fid = (b - BUCKET_BLOCKS - X2BF_BLOCKS) * 256 + threadIdx.x;
    if (fid >= 5 * 16384) return;
    int g = fid >> 14;
    int r = fid & 16383;
    int i = r & 7;
    int lane = (r >> 3) & 63;
    int ks = (r >> 9) & 3;
    int ct = r >> 11;
    int k = ks * 32 + (lane >> 4) * 8 + i;
    int col = ct * 16 + (lane & 15);
    const float* Wp = (g == 0) ? W0 : (g == 1) ? W1 : (g == 2) ? W2 : (g == 3) ? W3 : W4;
    float w = Wp[k * DD + col];
    unsigned short hi = f2bf(w);
    unsigned short lo = f2bf(w - bf2f(hi));
    wf[g * 32768 + r] = hi;
    wf[g * 32768 + 16384 + r] = lo;
  }
}

// ---------------- bf16 gather aggregation over buckets (32 lanes/row) ----------------
__global__ void k_aggr_bf(const ushort4* __restrict__ x, const int* __restrict__ cnt,
                          const unsigned short* __restrict__ bkt,
                          const int* __restrict__ ovfc, const unsigned* __restrict__ ovf,
                          ushort4* __restrict__ out) {
  int tid = blockIdx.x * 256 + threadIdx.x;
  int node = tid >> 5;
  if (node >= NN) return;
  int c = tid & 31;
  int cn = cnt[node];
  int ce = (cn < BSTRIDE) ? cn : BSTRIDE;
  const unsigned short* bp = bkt + (size_t)node * BSTRIDE;
  ushort4 sv = x[node * 32 + c];
  float ax = bf2f(sv.x), ay = bf2f(sv.y), az = bf2f(sv.z), aw = bf2f(sv.w);
  int j = 0;
  for (; j + 3 < ce; j += 4) {
    int s0 = bp[j], s1 = bp[j + 1], s2 = bp[j + 2], s3 = bp[j + 3];
    ushort4 v0 = x[s0 * 32 + c];
    ushort4 v1 = x[s1 * 32 + c];
    ushort4 v2 = x[s2 * 32 + c];
    ushort4 v3 = x[s3 * 32 + c];
    ax += bf2f(v0.x) + bf2f(v1.x) + bf2f(v2.x) + bf2f(v3.x);
    ay += bf2f(v0.y) + bf2f(v1.y) + bf2f(v2.y) + bf2f(v3.y);
    az += bf2f(v0.z) + bf2f(v1.z) + bf2f(v2.z) + bf2f(v3.z);
    aw += bf2f(v0.w) + bf2f(v1.w) + bf2f(v2.w) + bf2f(v3.w);
  }
  for (; j < ce; j++) {
    int s0 = bp[j];
    ushort4 v0 = x[s0 * 32 + c];
    ax += bf2f(v0.x); ay += bf2f(v0.y); az += bf2f(v0.z); aw += bf2f(v0.w);
  }
  if (cn > BSTRIDE) {                       // rare (~few nodes): scan overflow list
    int no = ovfc[0];
    if (no > OVF_MAX) no = OVF_MAX;
    for (int o = 0; o < no; o++) {
      unsigned pr = ovf[o];
      if ((int)(pr >> 16) == node) {
        ushort4 v0 = x[(int)(pr & 0xFFFFu) * 32 + c];
        ax += bf2f(v0.x); ay += bf2f(v0.y); az += bf2f(v0.z); aw += bf2f(v0.w);
      }
    }
  }
  ushort4 r;
  r.x = f2bf(ax); r.y = f2bf(ay); r.z = f2bf(az); r.w = f2bf(aw);
  out[node * 32 + c] = r;
}

// ------- MFMA GEMM, bf16 activations; W = hi+lo split (A*Whi + A*Wlo = A*W exact) ----
// 512 threads = 8 waves x 16 rows, 128 rows/block, grid 391 (r10 lesson: W-staging
// traffic scales with grid). W staged via async global_load_lds (overlaps A-prefetch).
template<bool BN_IN, bool RELU_OUT, bool STATS_OUT, bool HEAD>
__global__ __launch_bounds__(512) void k_mgemm(
    const unsigned short* __restrict__ in, const unsigned short* __restrict__ wf,
    const float* __restrict__ bias, float* __restrict__ outF,
    unsigned short* __restrict__ outB,
    const float* __restrict__ statsIn, float* __restrict__ statsOut,
    const float* __restrict__ gamma, const float* __restrict__ beta,
    const float* __restrict__ W2h, const float* __restrict__ b2h) {
  __shared__ __align__(16) char smem[65536];   // W frags; HEAD reuses as h-tile + W2
  __shared__ float scs[DD], shs[DD], lbias[DD], ls[DD], lq[DD];
  short* lw = (short*)smem;
  int tid = threadIdx.x;
  int lane = tid & 63, wv = tid >> 6;
  int rbase = blockIdx.x * 128 + wv * 16;
  int kq = (lane >> 4) * 8;

  // ---- W staging: async direct-to-LDS, 8 x 16B per thread ----
  {
    const float4* src = (const float4*)wf;
    float4* dst = (float4*)lw;
    int wbase = tid & ~63;                  // wave-uniform LDS base element
#pragma unroll
    for (int it = 0; it < 8; it++)
      gload_lds16(src + it * 512 + tid, dst + it * 512 + wbase);
  }

  // ---- A prefetch (overlaps with async staging) ----
  bf16x8 araw[4];
  {
    int row = rbase + (lane & 15);
    bool v = row < NN;
    const unsigned short* ap = in + (size_t)row * DD + kq;
    bf16x8 zz = {0, 0, 0, 0, 0, 0, 0, 0};
#pragma unroll
    for (int ks = 0; ks < 4; ks++)
      araw[ks] = v ? *(const bf16x8*)(ap + ks * 32) : zz;
  }

  if (tid < DD) {
    lbias[tid] = bias[tid];
    if (STATS_OUT) { ls[tid] = 0.f; lq[tid] = 0.f; }
    if (BN_IN) {
      float mu  = statsIn[tid] * (1.0f / NN);
      float var = statsIn[DD + tid] * (1.0f / NN) - mu * mu;
      float sc  = gamma[tid] * rsqrtf(var + BN_EPS_F);
      scs[tid] = sc;
      shs[tid] = beta[tid] - mu * sc;
    }
  }
  __syncthreads();

  bf16x8 ahi[4];
  if constexpr (BN_IN) {
#pragma unroll
    for (int ks = 0; ks < 4; ks++) {
      const float4* s4 = (const float4*)&scs[ks * 32 + kq];
      const float4* h4 = (const float4*)&shs[ks * 32 + kq];
      float4 sa = s4[0], sb = s4[1], ha = h4[0], hb = h4[1];
      float ss[8] = {sa.x, sa.y, sa.z, sa.w, sb.x, sb.y, sb.z, sb.w};
      float hh[8] = {ha.x, ha.y, ha.z, ha.w, hb.x, hb.y, hb.z, hb.w};
      bf16x8 h;
#pragma unroll
      for (int i = 0; i < 8; i++) {
        float xv = fmaxf(bf2f((unsigned short)araw[ks][i]) * ss[i] + hh[i], 0.f);
        h[i] = (short)f2bf(xv);
      }
      ahi[ks] = h;
    }
  } else {
#pragma unroll
    for (int ks = 0; ks < 4; ks++) ahi[ks] = araw[ks];
  }

  // ---- MFMA main loop: 64 MFMAs/wave ----
  f32x4 acc[8];
#pragma unroll
  for (int ct = 0; ct < 8; ct++) acc[ct] = (f32x4){0.f, 0.f, 0.f, 0.f};
  const bf16x8* lwv = (const bf16x8*)lw;
#pragma unroll
  for (int ks = 0; ks < 4; ks++) {
#pragma unroll
    for (int ct = 0; ct < 8; ct++) {
      bf16x8 bh = lwv[(ct * 4 + ks) * 64 + lane];
      bf16x8 bl = lwv[2048 + (ct * 4 + ks) * 64 + lane];
      acc[ct] = __builtin_amdgcn_mfma_f32_16x16x32_bf16(ahi[ks], bh, acc[ct], 0, 0, 0);
      acc[ct] = __builtin_amdgcn_mfma_f32_16x16x32_bf16(ahi[ks], bl, acc[ct], 0, 0, 0);
    }
  }

  // ---- epilogue ----  C/D layout: col = lane&15, row = (lane>>4)*4 + reg
  if constexpr (!HEAD) {
    int r0 = rbase + (lane >> 4) * 4;
#pragma unroll
    for (int ct = 0; ct < 8; ct++) {
      int col = ct * 16 + (lane & 15);
      float bb = lbias[col];
      float s = 0.f, q = 0.f;
#pragma unroll
      for (int j = 0; j < 4; j++) {
        int row = r0 + j;
        if (row < NN) {
          float v = acc[ct][j] + bb;
          if (RELU_OUT) v = fmaxf(v, 0.f);
          outB[(size_t)row * DD + col] = f2bf(v);
          if (STATS_OUT) { s += v; q += v * v; }
        }
      }
      if (STATS_OUT) {
        s += __shfl_xor(s, 16); s += __shfl_xor(s, 32);
        q += __shfl_xor(q, 16); q += __shfl_xor(q, 32);
        if ((lane >> 4) == 0) {
          atomicAdd(&ls[col], s);
          atomicAdd(&lq[col], q);
        }
      }
    }
    if (STATS_OUT) {
      __syncthreads();
      if (tid < DD) {
        atomicAdd(&statsOut[tid], ls[tid]);
        atomicAdd(&statsOut[DD + tid], lq[tid]);
      }
    }
  } else {
    // ---- fused head ----
    unsigned short* hs = (unsigned short*)smem;        // [128][132] bf16
    float* W2s = (float*)(smem + 33792);               // [128][40] f32
    __syncthreads();                                   // all waves done reading lw
    {
      int lr0 = wv * 16 + (lane >> 4) * 4;
#pragma unroll
      for (int ct = 0; ct < 8; ct++) {
        int col = ct * 16 + (lane & 15);
        float bb = lbias[col];
#pragma unroll
        for (int j = 0; j < 4; j++) {
          float v = fmaxf(acc[ct][j] + bb, 0.f);
          hs[(lr0 + j) * 132 + col] = f2bf(v);
        }
      }
      const float4* W2g = (const float4*)W2h;
      float4* W2s4 = (float4*)W2s;
#pragma unroll
      for (int it = 0; it < 3; it++) {
        int idx = it * 512 + tid;
        if (idx < 1280) W2s4[idx] = W2g[idx];
      }
    }
    __syncthreads();
    int lrow = tid >> 2, q = tid & 3;
    int grow = blockIdx.x * 128 + lrow;
    float a2[40];
#pragma unroll
    for (int j = 0; j < 40; j++) a2[j] = 0.f;
    for (int kk = 0; kk < 32; kk++) {
      int k = kk * 4 + q;
      float hv = bf2f(hs[lrow * 132 + k]);
      const float4* wrow = (const float4*)(W2s + k * DOUT);
#pragma unroll
      for (int j4 = 0; j4 < 10; j4++) {
        float4 w = wrow[j4];
        a2[j4 * 4 + 0] += hv * w.x;
        a2[j4 * 4 + 1] += hv * w.y;
        a2[j4 * 4 + 2] += hv * w.z;
        a2[j4 * 4 + 3] += hv * w.w;
      }
    }
#pragma unroll
    for (int j = 0; j < 40; j++) {
      a2[j] += __shfl_xor(a2[j], 1);
      a2[j] += __shfl_xor(a2[j], 2);
    }
    if (q == 0 && grow < NN) {
      const float4* b24 = (const float4*)b2h;
      float m = -INFINITY;
#pragma unroll
      for (int j4 = 0; j4 < 10; j4++) {
        float4 bb = b24[j4];
        a2[j4 * 4 + 0] += bb.x; a2[j4 * 4 + 1] += bb.y;
        a2[j4 * 4 + 2] += bb.z; a2[j4 * 4 + 3] += bb.w;
      }
#pragma unroll
      for (int j = 0; j < 40; j++) m = fmaxf(m, a2[j]);
      float s = 0.f;
#pragma unroll
      for (int j = 0; j < 40; j++) s += expf(a2[j] - m);
      float d = m + logf(s);
      float4* out4 = (float4*)(outF + (size_t)grow * DOUT);
#pragma unroll
      for (int j4 = 0; j4 < 10; j4++) {
        float4 v = make_float4(a2[j4 * 4 + 0] - d, a2[j4 * 4 + 1] - d,
                               a2[j4 * 4 + 2] - d, a2[j4 * 4 + 3] - d);
        out4[j4] = v;
      }
    }
  }
}

extern "C" void kernel_launch(void* const* d_in, const int* in_sizes, int n_in,
                              void* d_out, int out_size, void* d_ws, size_t ws_size,
                              hipStream_t stream) {
  const float* x   = (const float*)d_in[0];
  const int*   ei  = (const int*)d_in[1];
  const float* W1a = (const float*)d_in[2];
  const float* b1a = (const float*)d_in[3];
  const float* g1  = (const float*)d_in[4];
  const float* be1 = (const float*)d_in[5];
  const float* W2a = (const float*)d_in[6];
  const float* b2a = (const float*)d_in[7];
  const float* W1b = (const float*)d_in[8];
  const float* b1b = (const float*)d_in[9];
  const float* g2  = (const float*)d_in[10];
  const float* be2 = (const float*)d_in[11];
  const float* W2b = (const float*)d_in[12];
  const float* b2b = (const float*)d_in[13];
  const float* Wl1 = (const float*)d_in[14];
  const float* bl1 = (const float*)d_in[15];
  const float* Wl2 = (const float*)d_in[16];
  const float* bl2 = (const float*)d_in[17];
  float* out = (float*)d_out;

  unsigned short* bufX = (unsigned short*)d_ws;           // N x 128 bf16
  unsigned short* bufA = bufX + (size_t)NN * DD;          // N x 128 bf16
  unsigned short* bufB = bufA + (size_t)NN * DD;          // N x 128 bf16
  float* stats1 = (float*)(bufB + (size_t)NN * DD);       // 256
  float* stats2 = stats1 + 2 * DD;                        // 256
  int*   cnt    = (int*)(stats2 + 2 * DD);                // N
  int*   ovfc   = cnt + NN;                               // 4 (1 used)
  unsigned* ovf = (unsigned*)(ovfc + 4);                  // OVF_MAX
  unsigned short* bkt = (unsigned short*)(ovf + OVF_MAX); // N x BSTRIDE
  size_t wfOff = (((size_t)(bkt + (size_t)NN * BSTRIDE) - (size_t)d_ws) + 15) & ~(size_t)15;
  unsigned short* wfrag = (unsigned short*)((char*)d_ws + wfOff);

  const int* srcI = ei;
  const int* dstI = ei + NE;

  dim3 blk(256);
  int aggrGrid = (NN * 32 + 255) / 256;                  // 6250
  int gemmGrid = (NN + 127) / 128;                       // 391
  int bpGrid   = BUCKET_BLOCKS + X2BF_BLOCKS + WPREP_BLOCKS;
  int zeroGrid = (NN + 255) / 256;

  // ---- setup ----
  k_zero<<<zeroGrid, blk, 0, stream>>>(cnt, stats1, ovfc);
  k_bucketprep<<<bpGrid, blk, 0, stream>>>(srcI, dstI, cnt, bkt, ovfc, ovf,
                                           (const float4*)x, (ushort4*)bufX,
                                           W1a, W2a, W1b, W2b, Wl1, wfrag);

  // ---- conv1 ----
  k_aggr_bf<<<aggrGrid, blk, 0, stream>>>((const ushort4*)bufX, cnt, bkt, ovfc, ovf,
                                          (ushort4*)bufA);
  k_mgemm<false, false, true, false><<<gemmGrid, 512, 0, stream>>>(
      bufA, wfrag + 0 * 32768, b1a, nullptr, bufB,
      nullptr, stats1, nullptr, nullptr, nullptr, nullptr);
  k_mgemm<true, true, false, false><<<gemmGrid, 512, 0, stream>>>(
      bufB, wfrag + 1 * 32768, b2a, nullptr, bufA,
      stats1, nullptr, g1, be1, nullptr, nullptr);
  // ---- conv2 ----
  k_aggr_bf<<<aggrGrid, blk, 0, stream>>>((const ushort4*)bufA, cnt, bkt, ovfc, ovf,
                                          (ushort4*)bufB);
  k_mgemm<false, false, true, false><<<gemmGrid, 512, 0, stream>>>(
      bufB, wfrag + 2 * 32768, b1b, nullptr, bufA,
      nullptr, stats2, nullptr, nullptr, nullptr, nullptr);
  k_mgemm<true, true, false, false><<<gemmGrid, 512, 0, stream>>>(
      bufA, wfrag + 3 * 32768, b2b, nullptr, bufB,
      stats2, nullptr, g2, be2, nullptr, nullptr);
  // ---- fused head ----
  k_mgemm<false, false, true, true><<<gemmGrid, 512, 0, stream>>>(
      bufB, wfrag + 4 * 32768, bl1, out, nullptr,
      nullptr, nullptr, nullptr, nullptr, Wl2, bl2);
}

// Round 14
// 198.123 us; speedup vs baseline: 1.3176x; 1.0246x over previous
//
#include <hip/hip_runtime.h>
#include <math.h>

#define NN 50000
#define NE 800000
#define DD 128
#define DOUT 40
#define BN_EPS_F 1e-5f
#define BSTRIDE 32           // bucket row = one 64B line; overflow list for deg>32
#define OVF_MAX 8192
#define NPX (NN / 8)         // 6250 nodes per XCD partition
#define EPB 1024             // edges per chunk: 4 edges/thread via int4
#define BUCKET_BLOCKS (((NE + EPB - 1) / EPB) * 8)   // 6256
#define X2BF_BLOCKS 6250
#define WPREP_BLOCKS ((5 * 16384 + 255) / 256)       // 320

typedef __attribute__((ext_vector_type(8))) short bf16x8;
typedef __attribute__((ext_vector_type(4))) float f32x4;

static __device__ __forceinline__ unsigned short f2bf(float f) {
  unsigned u = __float_as_uint(f);
  unsigned r = (u + 0x7FFFu + ((u >> 16) & 1u)) >> 16;
  return (unsigned short)r;
}
static __device__ __forceinline__ float bf2f(unsigned short u) {
  return __uint_as_float((unsigned)u << 16);
}

// ---------------- zero cnt + stats + overflow counter ----------------
__global__ void k_zero(int* __restrict__ cnt, float* __restrict__ stats,
                       int* __restrict__ ovfc) {
  int i = blockIdx.x * 256 + threadIdx.x;
  if (i < NN) cnt[i] = 0;
  if (i < 4 * DD) stats[i] = 0.f;
  if (i == 0) ovfc[0] = 0;
}

// ---- fused: XCD-partitioned bucket build | x->bf16 | weight frag shuffle ----
__global__ void k_bucketprep(const int* __restrict__ srcI, const int* __restrict__ dstI,
                             int* __restrict__ cnt, unsigned short* __restrict__ bkt,
                             int* __restrict__ ovfc, unsigned* __restrict__ ovf,
                             const float4* __restrict__ x, ushort4* __restrict__ xb,
                             const float* __restrict__ W0, const float* __restrict__ W1,
                             const float* __restrict__ W2, const float* __restrict__ W3,
                             const float* __restrict__ W4, unsigned short* __restrict__ wf) {
  int b = blockIdx.x;
  if (b < BUCKET_BLOCKS) {
    int xcd = b & 7;
    int chunk = b >> 3;
    int lo = xcd * NPX, hi = lo + NPX;
    int e0 = chunk * EPB + threadIdx.x * 4;
    if (e0 < NE) {
      int4 d4 = *(const int4*)(dstI + e0);
      int4 s4 = *(const int4*)(srcI + e0);
      int dd[4] = {d4.x, d4.y, d4.z, d4.w};
      int ss[4] = {s4.x, s4.y, s4.z, s4.w};
#pragma unroll
      for (int i = 0; i < 4; i++) {
        int d = dd[i];
        if (d >= lo && d < hi) {
          int r = atomicAdd(&cnt[d], 1);
          if (r < BSTRIDE) {
            bkt[(size_t)d * BSTRIDE + r] = (unsigned short)ss[i];
          } else {
            int o = atomicAdd(ovfc, 1);
            if (o < OVF_MAX) ovf[o] = ((unsigned)d << 16) | (unsigned)ss[i];
          }
        }
      }
    }
  } else if (b < BUCKET_BLOCKS + X2BF_BLOCKS) {
    int i = (b - BUCKET_BLOCKS) * 256 + threadIdx.x;
    if (i < NN * 32) {
      float4 v = x[i];
      ushort4 r;
      r.x = f2bf(v.x); r.y = f2bf(v.y); r.z = f2bf(v.z); r.w = f2bf(v.w);
      xb[i] = r;
    }
  } else {
    int fid = (b - BUCKET_BLOCKS - X2BF_BLOCKS) * 256 + threadIdx.x;
    if (fid >= 5 * 16384) return;
    int g = fid >> 14;
    int r = fid & 16383;
    int i = r & 7;
    int lane = (r >> 3) & 63;
    int ks = (r >> 9) & 3;
    int ct = r >> 11;
    int k = ks * 32 + (lane >> 4) * 8 + i;
    int col = ct * 16 + (lane & 15);
    const float* Wp = (g == 0) ? W0 : (g == 1) ? W1 : (g == 2) ? W2 : (g == 3) ? W3 : W4;
    float w = Wp[k * DD + col];
    unsigned short hi = f2bf(w);
    unsigned short lo = f2bf(w - bf2f(hi));
    wf[g * 32768 + r] = hi;
    wf[g * 32768 + 16384 + r] = lo;    // lo kept in ws (unused by mgemm this round)
  }
}

// ---------------- bf16 gather aggregation over buckets (32 lanes/row) ----------------
__global__ void k_aggr_bf(const ushort4* __restrict__ x, const int* __restrict__ cnt,
                          const unsigned short* __restrict__ bkt,
                          const int* __restrict__ ovfc, const unsigned* __restrict__ ovf,
                          ushort4* __restrict__ out) {
  int tid = blockIdx.x * 256 + threadIdx.x;
  int node = tid >> 5;
  if (node >= NN) return;
  int c = tid & 31;
  int cn = cnt[node];
  int ce = (cn < BSTRIDE) ? cn : BSTRIDE;
  const unsigned short* bp = bkt + (size_t)node * BSTRIDE;
  ushort4 sv = x[node * 32 + c];
  float ax = bf2f(sv.x), ay = bf2f(sv.y), az = bf2f(sv.z), aw = bf2f(sv.w);
  int j = 0;
  for (; j + 3 < ce; j += 4) {
    int s0 = bp[j], s1 = bp[j + 1], s2 = bp[j + 2], s3 = bp[j + 3];
    ushort4 v0 = x[s0 * 32 + c];
    ushort4 v1 = x[s1 * 32 + c];
    ushort4 v2 = x[s2 * 32 + c];
    ushort4 v3 = x[s3 * 32 + c];
    ax += bf2f(v0.x) + bf2f(v1.x) + bf2f(v2.x) + bf2f(v3.x);
    ay += bf2f(v0.y) + bf2f(v1.y) + bf2f(v2.y) + bf2f(v3.y);
    az += bf2f(v0.z) + bf2f(v1.z) + bf2f(v2.z) + bf2f(v3.z);
    aw += bf2f(v0.w) + bf2f(v1.w) + bf2f(v2.w) + bf2f(v3.w);
  }
  for (; j < ce; j++) {
    int s0 = bp[j];
    ushort4 v0 = x[s0 * 32 + c];
    ax += bf2f(v0.x); ay += bf2f(v0.y); az += bf2f(v0.z); aw += bf2f(v0.w);
  }
  if (cn > BSTRIDE) {
    int no = ovfc[0];
    if (no > OVF_MAX) no = OVF_MAX;
    for (int o = 0; o < no; o++) {
      unsigned pr = ovf[o];
      if ((int)(pr >> 16) == node) {
        ushort4 v0 = x[(int)(pr & 0xFFFFu) * 32 + c];
        ax += bf2f(v0.x); ay += bf2f(v0.y); az += bf2f(v0.z); aw += bf2f(v0.w);
      }
    }
  }
  ushort4 r;
  r.x = f2bf(ax); r.y = f2bf(ay); r.z = f2bf(az); r.w = f2bf(aw);
  out[node * 32 + c] = r;
}

// ------- MFMA GEMM, bf16 activations, single-bf16 W (lo term dropped, r14) ----------
// 512 threads = 8 waves x 16 rows, 128 rows/block, grid 391. 32 KB W stage.
template<bool BN_IN, bool RELU_OUT, bool STATS_OUT, bool HEAD>
__global__ __launch_bounds__(512) void k_mgemm(
    const unsigned short* __restrict__ in, const unsigned short* __restrict__ wf,
    const float* __restrict__ bias, float* __restrict__ outF,
    unsigned short* __restrict__ outB,
    const float* __restrict__ statsIn, float* __restrict__ statsOut,
    const float* __restrict__ gamma, const float* __restrict__ beta,
    const float* __restrict__ W2h, const float* __restrict__ b2h) {
  __shared__ __align__(16) char smem[65536];   // [0,32K) W-hi frags; HEAD: h-tile + W2
  __shared__ float scs[DD], shs[DD], lbias[DD], ls[DD], lq[DD];
  short* lw = (short*)smem;
  int tid = threadIdx.x;
  int lane = tid & 63, wv = tid >> 6;
  int rbase = blockIdx.x * 128 + wv * 16;
  int kq = (lane >> 4) * 8;

  // ---- A prefetch (before W staging to overlap round trips) ----
  bf16x8 araw[4];
  {
    int row = rbase + (lane & 15);
    bool v = row < NN;
    const unsigned short* ap = in + (size_t)row * DD + kq;
    bf16x8 zz = {0, 0, 0, 0, 0, 0, 0, 0};
#pragma unroll
    for (int ks = 0; ks < 4; ks++)
      araw[ks] = v ? *(const bf16x8*)(ap + ks * 32) : zz;
  }

  // ---- W staging: 32 KB (hi only), 4 float4 per thread ----
  {
    const float4* src = (const float4*)wf;
    float4* dst = (float4*)lw;
#pragma unroll
    for (int it = 0; it < 4; it++) dst[it * 512 + tid] = src[it * 512 + tid];
  }
  if (tid < DD) {
    lbias[tid] = bias[tid];
    if (STATS_OUT) { ls[tid] = 0.f; lq[tid] = 0.f; }
    if (BN_IN) {
      float mu  = statsIn[tid] * (1.0f / NN);
      float var = statsIn[DD + tid] * (1.0f / NN) - mu * mu;
      float sc  = gamma[tid] * rsqrtf(var + BN_EPS_F);
      scs[tid] = sc;
      shs[tid] = beta[tid] - mu * sc;
    }
  }
  __syncthreads();

  bf16x8 ahi[4];
  if constexpr (BN_IN) {
#pragma unroll
    for (int ks = 0; ks < 4; ks++) {
      const float4* s4 = (const float4*)&scs[ks * 32 + kq];
      const float4* h4 = (const float4*)&shs[ks * 32 + kq];
      float4 sa = s4[0], sb = s4[1], ha = h4[0], hb = h4[1];
      float ss[8] = {sa.x, sa.y, sa.z, sa.w, sb.x, sb.y, sb.z, sb.w};
      float hh[8] = {ha.x, ha.y, ha.z, ha.w, hb.x, hb.y, hb.z, hb.w};
      bf16x8 h;
#pragma unroll
      for (int i = 0; i < 8; i++) {
        float xv = fmaxf(bf2f((unsigned short)araw[ks][i]) * ss[i] + hh[i], 0.f);
        h[i] = (short)f2bf(xv);
      }
      ahi[ks] = h;
    }
  } else {
#pragma unroll
    for (int ks = 0; ks < 4; ks++) ahi[ks] = araw[ks];
  }

  // ---- MFMA main loop: 32 MFMAs/wave (single-precision-W) ----
  f32x4 acc[8];
#pragma unroll
  for (int ct = 0; ct < 8; ct++) acc[ct] = (f32x4){0.f, 0.f, 0.f, 0.f};
  const bf16x8* lwv = (const bf16x8*)lw;
#pragma unroll
  for (int ks = 0; ks < 4; ks++) {
#pragma unroll
    for (int ct = 0; ct < 8; ct++) {
      bf16x8 bh = lwv[(ct * 4 + ks) * 64 + lane];
      acc[ct] = __builtin_amdgcn_mfma_f32_16x16x32_bf16(ahi[ks], bh, acc[ct], 0, 0, 0);
    }
  }

  // ---- epilogue ----  C/D layout: col = lane&15, row = (lane>>4)*4 + reg
  if constexpr (!HEAD) {
    int r0 = rbase + (lane >> 4) * 4;
#pragma unroll
    for (int ct = 0; ct < 8; ct++) {
      int col = ct * 16 + (lane & 15);
      float bb = lbias[col];
      float s = 0.f, q = 0.f;
#pragma unroll
      for (int j = 0; j < 4; j++) {
        int row = r0 + j;
        if (row < NN) {
          float v = acc[ct][j] + bb;
          if (RELU_OUT) v = fmaxf(v, 0.f);
          outB[(size_t)row * DD + col] = f2bf(v);
          if (STATS_OUT) { s += v; q += v * v; }
        }
      }
      if (STATS_OUT) {
        s += __shfl_xor(s, 16); s += __shfl_xor(s, 32);
        q += __shfl_xor(q, 16); q += __shfl_xor(q, 32);
        if ((lane >> 4) == 0) {
          atomicAdd(&ls[col], s);
          atomicAdd(&lq[col], q);
        }
      }
    }
    if (STATS_OUT) {
      __syncthreads();
      if (tid < DD) {
        atomicAdd(&statsOut[tid], ls[tid]);
        atomicAdd(&statsOut[DD + tid], lq[tid]);
      }
    }
  } else {
    // ---- fused head ----
    unsigned short* hs = (unsigned short*)smem;        // [128][132] bf16
    float* W2s = (float*)(smem + 33792);               // [128][40] f32
    __syncthreads();                                   // all waves done reading lw
    {
      int lr0 = wv * 16 + (lane >> 4) * 4;
#pragma unroll
      for (int ct = 0; ct < 8; ct++) {
        int col = ct * 16 + (lane & 15);
        float bb = lbias[col];
#pragma unroll
        for (int j = 0; j < 4; j++) {
          float v = fmaxf(acc[ct][j] + bb, 0.f);
          hs[(lr0 + j) * 132 + col] = f2bf(v);
        }
      }
      const float4* W2g = (const float4*)W2h;
      float4* W2s4 = (float4*)W2s;
#pragma unroll
      for (int it = 0; it < 3; it++) {
        int idx = it * 512 + tid;
        if (idx < 1280) W2s4[idx] = W2g[idx];
      }
    }
    __syncthreads();
    int lrow = tid >> 2, q = tid & 3;
    int grow = blockIdx.x * 128 + lrow;
    float a2[40];
#pragma unroll
    for (int j = 0; j < 40; j++) a2[j] = 0.f;
    for (int kk = 0; kk < 32; kk++) {
      int k = kk * 4 + q;
      float hv = bf2f(hs[lrow * 132 + k]);
      const float4* wrow = (const float4*)(W2s + k * DOUT);
#pragma unroll
      for (int j4 = 0; j4 < 10; j4++) {
        float4 w = wrow[j4];
        a2[j4 * 4 + 0] += hv * w.x;
        a2[j4 * 4 + 1] += hv * w.y;
        a2[j4 * 4 + 2] += hv * w.z;
        a2[j4 * 4 + 3] += hv * w.w;
      }
    }
#pragma unroll
    for (int j = 0; j < 40; j++) {
      a2[j] += __shfl_xor(a2[j], 1);
      a2[j] += __shfl_xor(a2[j], 2);
    }
    if (q == 0 && grow < NN) {
      const float4* b24 = (const float4*)b2h;
      float m = -INFINITY;
#pragma unroll
      for (int j4 = 0; j4 < 10; j4++) {
        float4 bb = b24[j4];
        a2[j4 * 4 + 0] += bb.x; a2[j4 * 4 + 1] += bb.y;
        a2[j4 * 4 + 2] += bb.z; a2[j4 * 4 + 3] += bb.w;
      }
#pragma unroll
      for (int j = 0; j < 40; j++) m = fmaxf(m, a2[j]);
      float s = 0.f;
#pragma unroll
      for (int j = 0; j < 40; j++) s += expf(a2[j] - m);
      float d = m + logf(s);
      float4* out4 = (float4*)(outF + (size_t)grow * DOUT);
#pragma unroll
      for (int j4 = 0; j4 < 10; j4++) {
        float4 v = make_float4(a2[j4 * 4 + 0] - d, a2[j4 * 4 + 1] - d,
                               a2[j4 * 4 + 2] - d, a2[j4 * 4 + 3] - d);
        out4[j4] = v;
      }
    }
  }
}

extern "C" void kernel_launch(void* const* d_in, const int* in_sizes, int n_in,
                              void* d_out, int out_size, void* d_ws, size_t ws_size,
                              hipStream_t stream) {
  const float* x   = (const float*)d_in[0];
  const int*   ei  = (const int*)d_in[1];
  const float* W1a = (const float*)d_in[2];
  const float* b1a = (const float*)d_in[3];
  const float* g1  = (const float*)d_in[4];
  const float* be1 = (const float*)d_in[5];
  const float* W2a = (const float*)d_in[6];
  const float* b2a = (const float*)d_in[7];
  const float* W1b = (const float*)d_in[8];
  const float* b1b = (const float*)d_in[9];
  const float* g2  = (const float*)d_in[10];
  const float* be2 = (const float*)d_in[11];
  const float* W2b = (const float*)d_in[12];
  const float* b2b = (const float*)d_in[13];
  const float* Wl1 = (const float*)d_in[14];
  const float* bl1 = (const float*)d_in[15];
  const float* Wl2 = (const float*)d_in[16];
  const float* bl2 = (const float*)d_in[17];
  float* out = (float*)d_out;

  unsigned short* bufX = (unsigned short*)d_ws;           // N x 128 bf16
  unsigned short* bufA = bufX + (size_t)NN * DD;          // N x 128 bf16
  unsigned short* bufB = bufA + (size_t)NN * DD;          // N x 128 bf16
  float* stats1 = (float*)(bufB + (size_t)NN * DD);       // 256
  float* stats2 = stats1 + 2 * DD;                        // 256
  int*   cnt    = (int*)(stats2 + 2 * DD);                // N
  int*   ovfc   = cnt + NN;                               // 4 (1 used)
  unsigned* ovf = (unsigned*)(ovfc + 4);                  // OVF_MAX
  unsigned short* bkt = (unsigned short*)(ovf + OVF_MAX); // N x BSTRIDE
  size_t wfOff = (((size_t)(bkt + (size_t)NN * BSTRIDE) - (size_t)d_ws) + 15) & ~(size_t)15;
  unsigned short* wfrag = (unsigned short*)((char*)d_ws + wfOff);

  const int* srcI = ei;
  const int* dstI = ei + NE;

  dim3 blk(256);
  int aggrGrid = (NN * 32 + 255) / 256;                  // 6250
  int gemmGrid = (NN + 127) / 128;                       // 391
  int bpGrid   = BUCKET_BLOCKS + X2BF_BLOCKS + WPREP_BLOCKS;
  int zeroGrid = (NN + 255) / 256;

  // ---- setup ----
  k_zero<<<zeroGrid, blk, 0, stream>>>(cnt, stats1, ovfc);
  k_bucketprep<<<bpGrid, blk, 0, stream>>>(srcI, dstI, cnt, bkt, ovfc, ovf,
                                           (const float4*)x, (ushort4*)bufX,
                                           W1a, W2a, W1b, W2b, Wl1, wfrag);

  // ---- conv1 ----
  k_aggr_bf<<<aggrGrid, blk, 0, stream>>>((const ushort4*)bufX, cnt, bkt, ovfc, ovf,
                                          (ushort4*)bufA);
  k_mgemm<false, false, true, false><<<gemmGrid, 512, 0, stream>>>(
      bufA, wfrag + 0 * 32768, b1a, nullptr, bufB,
      nullptr, stats1, nullptr, nullptr, nullptr, nullptr);
  k_mgemm<true, true, false, false><<<gemmGrid, 512, 0, stream>>>(
      bufB, wfrag + 1 * 32768, b2a, nullptr, bufA,
      stats1, nullptr, g1, be1, nullptr, nullptr);
  // ---- conv2 ----
  k_aggr_bf<<<aggrGrid, blk, 0, stream>>>((const ushort4*)bufA, cnt, bkt, ovfc, ovf,
                                          (ushort4*)bufB);
  k_mgemm<false, false, true, false><<<gemmGrid, 512, 0, stream>>>(
      bufB, wfrag + 2 * 32768, b1b, nullptr, bufA,
      nullptr, stats2, nullptr, nullptr, nullptr, nullptr);
  k_mgemm<true, true, false, false><<<gemmGrid, 512, 0, stream>>>(
      bufA, wfrag + 3 * 32768, b2b, nullptr, bufB,
      stats2, nullptr, g2, be2, nullptr, nullptr);
  // ---- fused head ----
  k_mgemm<false, false, true, true><<<gemmGrid, 512, 0, stream>>>(
      bufB, wfrag + 4 * 32768, bl1, out, nullptr,
      nullptr, nullptr, nullptr, nullptr, Wl2, bl2);
}

// Round 15
// 191.842 us; speedup vs baseline: 1.3607x; 1.0327x over previous
//
#include <hip/hip_runtime.h>
#include <math.h>

#define NN 50000
#define NE 800000
#define DD 128
#define DOUT 40
#define BN_EPS_F 1e-5f
#define BSTRIDE 32           // bucket row = one 64B line; overflow list for deg>32
#define OVF_MAX 8192
#define NPX (NN / 8)         // 6250 nodes per XCD partition
#define EPB 1024             // edges per chunk: 4 edges/thread via int4
#define BUCKET_BLOCKS (((NE + EPB - 1) / EPB) * 8)   // 6256
#define X2BF_BLOCKS 6250
#define WPREP_BLOCKS ((5 * 16384 + 255) / 256)       // 320
#define NSLOT 8              // BN-stats contention shards

typedef __attribute__((ext_vector_type(8))) short bf16x8;
typedef __attribute__((ext_vector_type(4))) float f32x4;

static __device__ __forceinline__ unsigned short f2bf(float f) {
  unsigned u = __float_as_uint(f);
  unsigned r = (u + 0x7FFFu + ((u >> 16) & 1u)) >> 16;
  return (unsigned short)r;
}
static __device__ __forceinline__ float bf2f(unsigned short u) {
  return __uint_as_float((unsigned)u << 16);
}

// ---------------- zero cnt + stats (2 x 8 slots x 256) + overflow counter ----------------
__global__ void k_zero(int* __restrict__ cnt, float* __restrict__ stats,
                       int* __restrict__ ovfc) {
  int i = blockIdx.x * 256 + threadIdx.x;
  if (i < NN) cnt[i] = 0;
  if (i < 2 * NSLOT * 2 * DD) stats[i] = 0.f;
  if (i == 0) ovfc[0] = 0;
}

// ---- fused: XCD-partitioned bucket build | x->bf16 | weight frag shuffle ----
__global__ void k_bucketprep(const int* __restrict__ srcI, const int* __restrict__ dstI,
                             int* __restrict__ cnt, unsigned short* __restrict__ bkt,
                             int* __restrict__ ovfc, unsigned* __restrict__ ovf,
                             const float4* __restrict__ x, ushort4* __restrict__ xb,
                             const float* __restrict__ W0, const float* __restrict__ W1,
                             const float* __restrict__ W2, const float* __restrict__ W3,
                             const float* __restrict__ W4, unsigned short* __restrict__ wf) {
  int b = blockIdx.x;
  if (b < BUCKET_BLOCKS) {
    int xcd = b & 7;
    int chunk = b >> 3;
    int lo = xcd * NPX, hi = lo + NPX;
    int e0 = chunk * EPB + threadIdx.x * 4;
    if (e0 < NE) {
      int4 d4 = *(const int4*)(dstI + e0);
      int4 s4 = *(const int4*)(srcI + e0);
      int dd[4] = {d4.x, d4.y, d4.z, d4.w};
      int ss[4] = {s4.x, s4.y, s4.z, s4.w};
#pragma unroll
      for (int i = 0; i < 4; i++) {
        int d = dd[i];
        if (d >= lo && d < hi) {
          int r = atomicAdd(&cnt[d], 1);
          if (r < BSTRIDE) {
            bkt[(size_t)d * BSTRIDE + r] = (unsigned short)ss[i];
          } else {
            int o = atomicAdd(ovfc, 1);
            if (o < OVF_MAX) ovf[o] = ((unsigned)d << 16) | (unsigned)ss[i];
          }
        }
      }
    }
  } else if (b < BUCKET_BLOCKS + X2BF_BLOCKS) {
    int i = (b - BUCKET_BLOCKS) * 256 + threadIdx.x;
    if (i < NN * 32) {
      float4 v = x[i];
      ushort4 r;
      r.x = f2bf(v.x); r.y = f2bf(v.y); r.z = f2bf(v.z); r.w = f2bf(v.w);
      xb[i] = r;
    }
  } else {
    int fid = (b - BUCKET_BLOCKS - X2BF_BLOCKS) * 256 + threadIdx.x;
    if (fid >= 5 * 16384) return;
    int g = fid >> 14;
    int r = fid & 16383;
    int i = r & 7;
    int lane = (r >> 3) & 63;
    int ks = (r >> 9) & 3;
    int ct = r >> 11;
    int k = ks * 32 + (lane >> 4) * 8 + i;
    int col = ct * 16 + (lane & 15);
    const float* Wp = (g == 0) ? W0 : (g == 1) ? W1 : (g == 2) ? W2 : (g == 3) ? W3 : W4;
    float w = Wp[k * DD + col];
    wf[g * 16384 + r] = f2bf(w);
  }
}

// ---------------- bf16 gather aggregation over buckets (32 lanes/row) ----------------
__global__ void k_aggr_bf(const ushort4* __restrict__ x, const int* __restrict__ cnt,
                          const unsigned short* __restrict__ bkt,
                          const int* __restrict__ ovfc, const unsigned* __restrict__ ovf,
                          ushort4* __restrict__ out) {
  int tid = blockIdx.x * 256 + threadIdx.x;
  int node = tid >> 5;
  if (node >= NN) return;
  int c = tid & 31;
  int cn = cnt[node];
  int ce = (cn < BSTRIDE) ? cn : BSTRIDE;
  const unsigned short* bp = bkt + (size_t)node * BSTRIDE;
  ushort4 sv = x[node * 32 + c];
  float ax = bf2f(sv.x), ay = bf2f(sv.y), az = bf2f(sv.z), aw = bf2f(sv.w);
  int j = 0;
  for (; j + 3 < ce; j += 4) {
    int s0 = bp[j], s1 = bp[j + 1], s2 = bp[j + 2], s3 = bp[j + 3];
    ushort4 v0 = x[s0 * 32 + c];
    ushort4 v1 = x[s1 * 32 + c];
    ushort4 v2 = x[s2 * 32 + c];
    ushort4 v3 = x[s3 * 32 + c];
    ax += bf2f(v0.x) + bf2f(v1.x) + bf2f(v2.x) + bf2f(v3.x);
    ay += bf2f(v0.y) + bf2f(v1.y) + bf2f(v2.y) + bf2f(v3.y);
    az += bf2f(v0.z) + bf2f(v1.z) + bf2f(v2.z) + bf2f(v3.z);
    aw += bf2f(v0.w) + bf2f(v1.w) + bf2f(v2.w) + bf2f(v3.w);
  }
  for (; j < ce; j++) {
    int s0 = bp[j];
    ushort4 v0 = x[s0 * 32 + c];
    ax += bf2f(v0.x); ay += bf2f(v0.y); az += bf2f(v0.z); aw += bf2f(v0.w);
  }
  if (cn > BSTRIDE) {
    int no = ovfc[0];
    if (no > OVF_MAX) no = OVF_MAX;
    for (int o = 0; o < no; o++) {
      unsigned pr = ovf[o];
      if ((int)(pr >> 16) == node) {
        ushort4 v0 = x[(int)(pr & 0xFFFFu) * 32 + c];
        ax += bf2f(v0.x); ay += bf2f(v0.y); az += bf2f(v0.z); aw += bf2f(v0.w);
      }
    }
  }
  ushort4 r;
  r.x = f2bf(ax); r.y = f2bf(ay); r.z = f2bf(az); r.w = f2bf(aw);
  out[node * 32 + c] = r;
}

// ------- MFMA GEMM, bf16 activations, single-bf16 W ----------
// 512 threads = 8 waves x 16 rows, 128 rows/block, grid 391.
// smem template-sized: 32 KB (W stage) non-HEAD -> 4 blocks/CU; 54 KB HEAD (r15).
// BN stats sharded over NSLOT slots (blockIdx&7) to cut atomic contention (r15).
template<bool BN_IN, bool RELU_OUT, bool STATS_OUT, bool HEAD>
__global__ __launch_bounds__(512) void k_mgemm(
    const unsigned short* __restrict__ in, const unsigned short* __restrict__ wf,
    const float* __restrict__ bias, float* __restrict__ outF,
    unsigned short* __restrict__ outB,
    const float* __restrict__ statsIn, float* __restrict__ statsOut,
    const float* __restrict__ gamma, const float* __restrict__ beta,
    const float* __restrict__ W2h, const float* __restrict__ b2h) {
  constexpr int SMEM_BYTES = HEAD ? 54272 : 32768;
  __shared__ __align__(16) char smem[SMEM_BYTES];
  __shared__ float scs[DD], shs[DD], lbias[DD], ls[DD], lq[DD];
  short* lw = (short*)smem;
  int tid = threadIdx.x;
  int lane = tid & 63, wv = tid >> 6;
  int rbase = blockIdx.x * 128 + wv * 16;
  int kq = (lane >> 4) * 8;

  // ---- A prefetch (before W staging to overlap round trips) ----
  bf16x8 araw[4];
  {
    int row = rbase + (lane & 15);
    bool v = row < NN;
    const unsigned short* ap = in + (size_t)row * DD + kq;
    bf16x8 zz = {0, 0, 0, 0, 0, 0, 0, 0};
#pragma unroll
    for (int ks = 0; ks < 4; ks++)
      araw[ks] = v ? *(const bf16x8*)(ap + ks * 32) : zz;
  }

  // ---- W staging: 32 KB, 4 float4 per thread ----
  {
    const float4* src = (const float4*)wf;
    float4* dst = (float4*)lw;
#pragma unroll
    for (int it = 0; it < 4; it++) dst[it * 512 + tid] = src[it * 512 + tid];
  }
  if (tid < DD) {
    lbias[tid] = bias[tid];
    if (STATS_OUT) { ls[tid] = 0.f; lq[tid] = 0.f; }
    if (BN_IN) {
      float su = 0.f, sq = 0.f;
#pragma unroll
      for (int s = 0; s < NSLOT; s++) {
        su += statsIn[s * 2 * DD + tid];
        sq += statsIn[s * 2 * DD + DD + tid];
      }
      float mu  = su * (1.0f / NN);
      float var = sq * (1.0f / NN) - mu * mu;
      float sc  = gamma[tid] * rsqrtf(var + BN_EPS_F);
      scs[tid] = sc;
      shs[tid] = beta[tid] - mu * sc;
    }
  }
  __syncthreads();

  bf16x8 ahi[4];
  if constexpr (BN_IN) {
#pragma unroll
    for (int ks = 0; ks < 4; ks++) {
      const float4* s4 = (const float4*)&scs[ks * 32 + kq];
      const float4* h4 = (const float4*)&shs[ks * 32 + kq];
      float4 sa = s4[0], sb = s4[1], ha = h4[0], hb = h4[1];
      float ss[8] = {sa.x, sa.y, sa.z, sa.w, sb.x, sb.y, sb.z, sb.w};
      float hh[8] = {ha.x, ha.y, ha.z, ha.w, hb.x, hb.y, hb.z, hb.w};
      bf16x8 h;
#pragma unroll
      for (int i = 0; i < 8; i++) {
        float xv = fmaxf(bf2f((unsigned short)araw[ks][i]) * ss[i] + hh[i], 0.f);
        h[i] = (short)f2bf(xv);
      }
      ahi[ks] = h;
    }
  } else {
#pragma unroll
    for (int ks = 0; ks < 4; ks++) ahi[ks] = araw[ks];
  }

  // ---- MFMA main loop: 32 MFMAs/wave ----
  f32x4 acc[8];
#pragma unroll
  for (int ct = 0; ct < 8; ct++) acc[ct] = (f32x4){0.f, 0.f, 0.f, 0.f};
  const bf16x8* lwv = (const bf16x8*)lw;
#pragma unroll
  for (int ks = 0; ks < 4; ks++) {
#pragma unroll
    for (int ct = 0; ct < 8; ct++) {
      bf16x8 bh = lwv[(ct * 4 + ks) * 64 + lane];
      acc[ct] = __builtin_amdgcn_mfma_f32_16x16x32_bf16(ahi[ks], bh, acc[ct], 0, 0, 0);
    }
  }

  // ---- epilogue ----  C/D layout: col = lane&15, row = (lane>>4)*4 + reg
  if constexpr (!HEAD) {
    int r0 = rbase + (lane >> 4) * 4;
#pragma unroll
    for (int ct = 0; ct < 8; ct++) {
      int col = ct * 16 + (lane & 15);
      float bb = lbias[col];
      float s = 0.f, q = 0.f;
#pragma unroll
      for (int j = 0; j < 4; j++) {
        int row = r0 + j;
        if (row < NN) {
          float v = acc[ct][j] + bb;
          if (RELU_OUT) v = fmaxf(v, 0.f);
          outB[(size_t)row * DD + col] = f2bf(v);
          if (STATS_OUT) { s += v; q += v * v; }
        }
      }
      if (STATS_OUT) {
        s += __shfl_xor(s, 16); s += __shfl_xor(s, 32);
        q += __shfl_xor(q, 16); q += __shfl_xor(q, 32);
        if ((lane >> 4) == 0) {
          atomicAdd(&ls[col], s);
          atomicAdd(&lq[col], q);
        }
      }
    }
    if (STATS_OUT) {
      __syncthreads();
      if (tid < DD) {
        float* slot = statsOut + (blockIdx.x & (NSLOT - 1)) * 2 * DD;
        atomicAdd(&slot[tid], ls[tid]);
        atomicAdd(&slot[DD + tid], lq[tid]);
      }
    }
  } else {
    // ---- fused head ----
    unsigned short* hs = (unsigned short*)smem;        // [128][132] bf16
    float* W2s = (float*)(smem + 33792);               // [128][40] f32
    __syncthreads();                                   // all waves done reading lw
    {
      int lr0 = wv * 16 + (lane >> 4) * 4;
#pragma unroll
      for (int ct = 0; ct < 8; ct++) {
        int col = ct * 16 + (lane & 15);
        float bb = lbias[col];
#pragma unroll
        for (int j = 0; j < 4; j++) {
          float v = fmaxf(acc[ct][j] + bb, 0.f);
          hs[(lr0 + j) * 132 + col] = f2bf(v);
        }
      }
      const float4* W2g = (const float4*)W2h;
      float4* W2s4 = (float4*)W2s;
#pragma unroll
      for (int it = 0; it < 3; it++) {
        int idx = it * 512 + tid;
        if (idx < 1280) W2s4[idx] = W2g[idx];
      }
    }
    __syncthreads();
    int lrow = tid >> 2, q = tid & 3;
    int grow = blockIdx.x * 128 + lrow;
    float a2[40];
#pragma unroll
    for (int j = 0; j < 40; j++) a2[j] = 0.f;
    for (int kk = 0; kk < 32; kk++) {
      int k = kk * 4 + q;
      float hv = bf2f(hs[lrow * 132 + k]);
      const float4* wrow = (const float4*)(W2s + k * DOUT);
#pragma unroll
      for (int j4 = 0; j4 < 10; j4++) {
        float4 w = wrow[j4];
        a2[j4 * 4 + 0] += hv * w.x;
        a2[j4 * 4 + 1] += hv * w.y;
        a2[j4 * 4 + 2] += hv * w.z;
        a2[j4 * 4 + 3] += hv * w.w;
      }
    }
#pragma unroll
    for (int j = 0; j < 40; j++) {
      a2[j] += __shfl_xor(a2[j], 1);
      a2[j] += __shfl_xor(a2[j], 2);
    }
    if (q == 0 && grow < NN) {
      const float4* b24 = (const float4*)b2h;
      float m = -INFINITY;
#pragma unroll
      for (int j4 = 0; j4 < 10; j4++) {
        float4 bb = b24[j4];
        a2[j4 * 4 + 0] += bb.x; a2[j4 * 4 + 1] += bb.y;
        a2[j4 * 4 + 2] += bb.z; a2[j4 * 4 + 3] += bb.w;
      }
#pragma unroll
      for (int j = 0; j < 40; j++) m = fmaxf(m, a2[j]);
      float s = 0.f;
#pragma unroll
      for (int j = 0; j < 40; j++) s += expf(a2[j] - m);
      float d = m + logf(s);
      float4* out4 = (float4*)(outF + (size_t)grow * DOUT);
#pragma unroll
      for (int j4 = 0; j4 < 10; j4++) {
        float4 v = make_float4(a2[j4 * 4 + 0] - d, a2[j4 * 4 + 1] - d,
                               a2[j4 * 4 + 2] - d, a2[j4 * 4 + 3] - d);
        out4[j4] = v;
      }
    }
  }
}

extern "C" void kernel_launch(void* const* d_in, const int* in_sizes, int n_in,
                              void* d_out, int out_size, void* d_ws, size_t ws_size,
                              hipStream_t stream) {
  const float* x   = (const float*)d_in[0];
  const int*   ei  = (const int*)d_in[1];
  const float* W1a = (const float*)d_in[2];
  const float* b1a = (const float*)d_in[3];
  const float* g1  = (const float*)d_in[4];
  const float* be1 = (const float*)d_in[5];
  const float* W2a = (const float*)d_in[6];
  const float* b2a = (const float*)d_in[7];
  const float* W1b = (const float*)d_in[8];
  const float* b1b = (const float*)d_in[9];
  const float* g2  = (const float*)d_in[10];
  const float* be2 = (const float*)d_in[11];
  const float* W2b = (const float*)d_in[12];
  const float* b2b = (const float*)d_in[13];
  const float* Wl1 = (const float*)d_in[14];
  const float* bl1 = (const float*)d_in[15];
  const float* Wl2 = (const float*)d_in[16];
  const float* bl2 = (const float*)d_in[17];
  float* out = (float*)d_out;

  unsigned short* bufX = (unsigned short*)d_ws;           // N x 128 bf16
  unsigned short* bufA = bufX + (size_t)NN * DD;          // N x 128 bf16
  unsigned short* bufB = bufA + (size_t)NN * DD;          // N x 128 bf16
  float* stats1 = (float*)(bufB + (size_t)NN * DD);       // NSLOT x 256
  float* stats2 = stats1 + NSLOT * 2 * DD;                // NSLOT x 256
  int*   cnt    = (int*)(stats2 + NSLOT * 2 * DD);        // N
  int*   ovfc   = cnt + NN;                               // 4 (1 used)
  unsigned* ovf = (unsigned*)(ovfc + 4);                  // OVF_MAX
  unsigned short* bkt = (unsigned short*)(ovf + OVF_MAX); // N x BSTRIDE
  size_t wfOff = (((size_t)(bkt + (size_t)NN * BSTRIDE) - (size_t)d_ws) + 15) & ~(size_t)15;
  unsigned short* wfrag = (unsigned short*)((char*)d_ws + wfOff);   // 5 x 16384 bf16

  const int* srcI = ei;
  const int* dstI = ei + NE;

  dim3 blk(256);
  int aggrGrid = (NN * 32 + 255) / 256;                  // 6250
  int gemmGrid = (NN + 127) / 128;                       // 391
  int bpGrid   = BUCKET_BLOCKS + X2BF_BLOCKS + WPREP_BLOCKS;
  int zeroGrid = (NN + 255) / 256;

  // ---- setup ----
  k_zero<<<zeroGrid, blk, 0, stream>>>(cnt, stats1, ovfc);
  k_bucketprep<<<bpGrid, blk, 0, stream>>>(srcI, dstI, cnt, bkt, ovfc, ovf,
                                           (const float4*)x, (ushort4*)bufX,
                                           W1a, W2a, W1b, W2b, Wl1, wfrag);

  // ---- conv1 ----
  k_aggr_bf<<<aggrGrid, blk, 0, stream>>>((const ushort4*)bufX, cnt, bkt, ovfc, ovf,
                                          (ushort4*)bufA);
  k_mgemm<false, false, true, false><<<gemmGrid, 512, 0, stream>>>(
      bufA, wfrag + 0 * 16384, b1a, nullptr, bufB,
      nullptr, stats1, nullptr, nullptr, nullptr, nullptr);
  k_mgemm<true, true, false, false><<<gemmGrid, 512, 0, stream>>>(
      bufB, wfrag + 1 * 16384, b2a, nullptr, bufA,
      stats1, nullptr, g1, be1, nullptr, nullptr);
  // ---- conv2 ----
  k_aggr_bf<<<aggrGrid, blk, 0, stream>>>((const ushort4*)bufA, cnt, bkt, ovfc, ovf,
                                          (ushort4*)bufB);
  k_mgemm<false, false, true, false><<<gemmGrid, 512, 0, stream>>>(
      bufB, wfrag + 2 * 16384, b1b, nullptr, bufA,
      nullptr, stats2, nullptr, nullptr, nullptr, nullptr);
  k_mgemm<true, true, false, false><<<gemmGrid, 512, 0, stream>>>(
      bufA, wfrag + 3 * 16384, b2b, nullptr, bufB,
      stats2, nullptr, g2, be2, nullptr, nullptr);
  // ---- fused head ----
  k_mgemm<false, false, true, true><<<gemmGrid, 512, 0, stream>>>(
      bufB, wfrag + 4 * 16384, bl1, out, nullptr,
      nullptr, nullptr, nullptr, nullptr, Wl2, bl2);
}